// Round 1
// baseline (453.239 us; speedup 1.0000x reference)
//
#include <hip/hip_runtime.h>
#include <stdint.h>

#define NROWS 262144
#define DDIM 128
#define NCLS 512
constexpr float INV_BETA = 10.0f;

typedef __bf16 v8bf __attribute__((ext_vector_type(8)));
typedef float v4f __attribute__((ext_vector_type(4)));

__device__ inline unsigned short f2bf(float f) {
    uint32_t u = __builtin_bit_cast(uint32_t, f);
    u += 0x7FFFu + ((u >> 16) & 1u);
    return (unsigned short)(u >> 16);
}
__device__ inline float bf2f(unsigned short h) {
    uint32_t u = ((uint32_t)h) << 16;
    return __builtin_bit_cast(float, u);
}

// K1: L2-normalize rows of inputs, write bf16; count classes.
// Half-wave (32 lanes) per row; float4 per lane (16B).
__global__ __launch_bounds__(256) void k1_normalize(
    const float* __restrict__ in, const int* __restrict__ tgt,
    unsigned short* __restrict__ xb, int* __restrict__ counts) {
    int t = threadIdx.x;
    int l = t & 63;
    int w = t >> 6;
    int half = l >> 5;
    int lane32 = l & 31;
    for (int row = blockIdx.x * 8 + w * 2 + half; row < NROWS; row += gridDim.x * 8) {
        const float4 v = *reinterpret_cast<const float4*>(in + (size_t)row * DDIM + lane32 * 4);
        float ss = v.x * v.x + v.y * v.y + v.z * v.z + v.w * v.w;
        for (int off = 1; off < 32; off <<= 1) ss += __shfl_xor(ss, off);
        float inv = 1.0f / fmaxf(sqrtf(ss), 1e-12f);
        ushort4 o;
        o.x = f2bf(v.x * inv); o.y = f2bf(v.y * inv);
        o.z = f2bf(v.z * inv); o.w = f2bf(v.w * inv);
        *reinterpret_cast<ushort4*>(xb + (size_t)row * DDIM + lane32 * 4) = o;
        if (lane32 == 0) atomicAdd(counts + tgt[row], 1);
    }
}

// K2: per-class sums, LDS-privatized. blockIdx: dc = &3 (dim chunk of 32),
// slice = >>2 (row slice of 4096). LDS tile 512x32 f32, bank-swizzled.
__global__ __launch_bounds__(256) void k2_csum(
    const unsigned short* __restrict__ xb, const int* __restrict__ tgt,
    float* __restrict__ partial) {
    extern __shared__ float tile[];  // 512*32 floats = 64 KB
    int t = threadIdx.x;
    int dc = blockIdx.x & 3;
    int slice = blockIdx.x >> 2;
    for (int i = t; i < NCLS * 32; i += 256) tile[i] = 0.0f;
    __syncthreads();
    int row0 = slice * (NROWS / 64);
    int g = t & 7;      // dim group (4 dims each)
    int rsub = t >> 3;  // 0..31 rows per iter
    for (int it = 0; it < (NROWS / 64) / 32; ++it) {
        int row = row0 + it * 32 + rsub;
        const ushort4 v = *reinterpret_cast<const ushort4*>(xb + (size_t)row * DDIM + dc * 32 + g * 4);
        int c = tgt[row];
        int sw = (c & 7) << 2;
        // dim_in_chunk = g*4+j stored at perm(dim)=j*8+g, XOR class swizzle
        atomicAdd(&tile[c * 32 + ((0 * 8 + g) ^ sw)], bf2f(v.x));
        atomicAdd(&tile[c * 32 + ((1 * 8 + g) ^ sw)], bf2f(v.y));
        atomicAdd(&tile[c * 32 + ((2 * 8 + g) ^ sw)], bf2f(v.z));
        atomicAdd(&tile[c * 32 + ((3 * 8 + g) ^ sw)], bf2f(v.w));
    }
    __syncthreads();
    float* outp = partial + (size_t)blockIdx.x * (NCLS * 32);
    for (int i = t; i < NCLS * 32; i += 256) {
        int c = i >> 5, dim = i & 31;
        int pd = ((dim & 3) << 3) | (dim >> 2);  // perm(dim)
        outp[i] = tile[c * 32 + (pd ^ ((c & 7) << 2))];
    }
}

// K3: reduce partials over 64 slices, mean, L2-normalize, write bf16 centers.
__global__ __launch_bounds__(128) void k3_centers(
    const float* __restrict__ partial, const int* __restrict__ counts,
    unsigned short* __restrict__ cen, float* __restrict__ present) {
    int c = blockIdx.x;
    int d = threadIdx.x;  // 0..127
    int dc = d >> 5, dim = d & 31;
    float s = 0.0f;
    for (int sl = 0; sl < 64; ++sl)
        s += partial[(size_t)(sl * 4 + dc) * (NCLS * 32) + c * 32 + dim];
    int cnt = counts[c];
    float cm = s / fmaxf((float)cnt, 1.0f);
    float ss = cm * cm;
    for (int off = 1; off < 64; off <<= 1) ss += __shfl_xor(ss, off);
    __shared__ float red[2];
    if ((d & 63) == 0) red[d >> 6] = ss;
    __syncthreads();
    float tot = red[0] + red[1];
    float inv = 1.0f / fmaxf(sqrtf(tot), 1e-12f);
    cen[(size_t)c * DDIM + d] = f2bf(cm * inv);
    if (d == 0) present[c] = (cnt > 0) ? 1.0f : 0.0f;
}

// K4: per block: 64 samples x all 512 classes. Centers (128KB, swizzled) +
// x tile (16KB, swizzled) in LDS. 8 waves, wave w owns classes [w*64,w*64+64).
__global__ __launch_bounds__(512) void k4_loss(
    const unsigned short* __restrict__ xb, const unsigned short* __restrict__ cen,
    const float* __restrict__ present, const int* __restrict__ tgt,
    float* __restrict__ out) {
    extern __shared__ char lds[];
    char* cenL = lds;                          // 131072 B
    char* xL = lds + 131072;                   // 16384 B
    float* prsL = (float*)(lds + 147456);      // 512 f32
    int* tgtL = (int*)(lds + 149504);          // 64 int
    float* denL = (float*)(lds + 149760);      // 64 f32
    float* posL = (float*)(lds + 150016);      // 64 f32
    int t = threadIdx.x;
    int base = blockIdx.x * 64;

    // stage centers: 8192 16B-chunks, coalesced, swizzled dst
    for (int i = 0; i < 16; ++i) {
        int chunk = i * 512 + t;
        int row = chunk >> 4, c16 = chunk & 15;
        uint4 v = *reinterpret_cast<const uint4*>((const char*)cen + (size_t)chunk * 16);
        *reinterpret_cast<uint4*>(cenL + row * 256 + ((c16 * 16) ^ ((row & 7) << 4))) = v;
    }
    // stage x tile: 1024 16B-chunks
    for (int i = 0; i < 2; ++i) {
        int chunk = i * 512 + t;
        int row = chunk >> 4, c16 = chunk & 15;
        uint4 v = *reinterpret_cast<const uint4*>((const char*)xb + (size_t)base * 256 + (size_t)chunk * 16);
        *reinterpret_cast<uint4*>(xL + row * 256 + ((c16 * 16) ^ ((row & 7) << 4))) = v;
    }
    prsL[t & 511] = present[t & 511];
    if (t < 64) { tgtL[t] = tgt[base + t]; denL[t] = 0.0f; posL[t] = 0.0f; }
    __syncthreads();

    int w = t >> 6, l = t & 63;
    int lm = l & 15, lk = l >> 4;
    v4f acc[4][4];
    v4f zero = {0.0f, 0.0f, 0.0f, 0.0f};
#pragma unroll
    for (int m = 0; m < 4; ++m)
#pragma unroll
        for (int n = 0; n < 4; ++n) acc[m][n] = zero;

#pragma unroll
    for (int kc = 0; kc < 4; ++kc) {
        int kb = kc * 64 + lk * 16;
        v8bf a[4], b[4];
#pragma unroll
        for (int m = 0; m < 4; ++m) {
            int row = w * 64 + m * 16 + lm;
            a[m] = *reinterpret_cast<const v8bf*>(cenL + row * 256 + (kb ^ ((row & 7) << 4)));
        }
#pragma unroll
        for (int n = 0; n < 4; ++n) {
            int row = n * 16 + lm;
            b[n] = *reinterpret_cast<const v8bf*>(xL + row * 256 + (kb ^ ((row & 7) << 4)));
        }
#pragma unroll
        for (int m = 0; m < 4; ++m)
#pragma unroll
            for (int n = 0; n < 4; ++n)
                acc[m][n] = __builtin_amdgcn_mfma_f32_16x16x32_bf16(a[m], b[n], acc[m][n], 0, 0, 0);
    }

    // epilogue: per sample-col, sum exp over this wave's 64 classes + pick pos
#pragma unroll
    for (int n = 0; n < 4; ++n) {
        int s = n * 16 + lm;
        int ts = tgtL[s];
        float se = 0.0f, sp = 0.0f;
#pragma unroll
        for (int m = 0; m < 4; ++m) {
#pragma unroll
            for (int r = 0; r < 4; ++r) {
                int cls = w * 64 + m * 16 + lk * 4 + r;
                float logit = acc[m][n][r] * INV_BETA;
                se += prsL[cls] * __expf(logit);
                if (cls == ts) sp = logit;
            }
        }
        se += __shfl_xor(se, 16); se += __shfl_xor(se, 32);
        sp += __shfl_xor(sp, 16); sp += __shfl_xor(sp, 32);
        if (l < 16) { atomicAdd(&denL[s], se); atomicAdd(&posL[s], sp); }
    }
    __syncthreads();
    if (t < 64) {
        float li = __logf(denL[t]) - posL[t];
        for (int off = 1; off < 64; off <<= 1) li += __shfl_xor(li, off);
        if (t == 0) atomicAdd(out, li * (1.0f / NROWS));
    }
}

extern "C" void kernel_launch(void* const* d_in, const int* in_sizes, int n_in,
                              void* d_out, int out_size, void* d_ws, size_t ws_size,
                              hipStream_t stream) {
    const float* in = (const float*)d_in[0];
    const int* tgt = (const int*)d_in[1];
    float* out = (float*)d_out;
    char* ws = (char*)d_ws;
    unsigned short* xb = (unsigned short*)(ws);              // 67108864 B
    int* counts = (int*)(ws + 67108864);                     // 2048 B
    unsigned short* cen = (unsigned short*)(ws + 67110912);  // 131072 B
    float* present = (float*)(ws + 67241984);                // 2048 B
    float* partial = (float*)(ws + 67244032);                // 16777216 B

    (void)hipFuncSetAttribute((const void*)k4_loss,
                              hipFuncAttributeMaxDynamicSharedMemorySize, 150272);

    hipMemsetAsync(counts, 0, 2048, stream);
    hipMemsetAsync(out, 0, sizeof(float), stream);
    hipLaunchKernelGGL(k1_normalize, dim3(2048), dim3(256), 0, stream, in, tgt, xb, counts);
    hipLaunchKernelGGL(k2_csum, dim3(256), dim3(256), 65536, stream, xb, tgt, partial);
    hipLaunchKernelGGL(k3_centers, dim3(512), dim3(128), 0, stream, partial, counts, cen, present);
    hipLaunchKernelGGL(k4_loss, dim3(4096), dim3(512), 150272, stream, xb, cen, present, tgt, out);
}